// Round 6
// baseline (299.187 us; speedup 1.0000x reference)
//
#include <hip/hip_runtime.h>
#include <hip/hip_fp16.h>

// WordAttention on MI355X: fp16 MFMA pipeline.
//   q,k,v = x@W + b (fp16);  S = q k^T (fp16, z=8);  P = softmax(S) in-place;  out = P v (fp32, z=8)
// proj + scores: 256x256 GEMM, 2 MH-phases/K-tile with bf-persistence + af read-ahead
//   (24 ds_read_b128 per K-tile per wave vs 48), counted vmcnt(4) + counted lgkmcnt(8).
// PV: 128x128 BK=64 depth-2 counted-vmcnt pipeline, swizzled LDS, asm reads.
// All GEMM grids XCD-swizzled (T1) for L2 locality.

typedef _Float16 f16;
typedef __attribute__((ext_vector_type(8))) _Float16 f16x8;
typedef __attribute__((ext_vector_type(4))) _Float16 f16x4;
typedef __attribute__((ext_vector_type(4))) float f32x4;
typedef __attribute__((address_space(3))) char lds_t;

#define GADDR(p) ((const __attribute__((address_space(1))) void*)(p))
#define LADDR(p) ((__attribute__((address_space(3))) void*)(p))

__device__ __forceinline__ unsigned lds_u32(void* p) {
    return (unsigned)(unsigned long long)(lds_t*)p;
}

// asm ds_read_b128: opaque to alias analysis; caller provides counted lgkmcnt waits.
#define DSRD(dst, a) asm volatile("ds_read_b128 %0, %1" : "=v"(dst) : "v"(a))
#define WAITV0 asm volatile("s_waitcnt vmcnt(0)" ::: "memory")
#define WAITV4 asm volatile("s_waitcnt vmcnt(4)" ::: "memory")
#define WAITV8 asm volatile("s_waitcnt vmcnt(8)" ::: "memory")
#define WAITLG(n) asm volatile("s_waitcnt lgkmcnt(" #n ")" ::: "memory")

// T1: XCD-aware bijective remap (requires nwg % 8 == 0; all our grids satisfy).
__device__ __forceinline__ void xcd_remap(int& bx, int& by, int& bz) {
    const int gx = gridDim.x, gy = gridDim.y;
    const int nwg = gx * gy * gridDim.z;
    const int f = (blockIdx.z * gy + blockIdx.y) * gx + blockIdx.x;
    int L = (f & 7) * (nwg >> 3) + (f >> 3);
    bx = L % gx; int r = L / gx; by = r % gy; bz = r / gy;
}

// ---------------- convert x: fp32 -> fp16 ----------------
__global__ __launch_bounds__(256) void k_cvt_x(const float* __restrict__ in,
                                               f16* __restrict__ out) {
    long i = (long)blockIdx.x * 256 + threadIdx.x;
    float4 v = ((const float4*)in)[i];
    f16x4 h = { (f16)v.x, (f16)v.y, (f16)v.z, (f16)v.w };
    ((f16x4*)out)[i] = h;
}

// ------------- convert+transpose weights: Wt[w][n][k] = W[w][k][n] -------------
__global__ __launch_bounds__(256) void k_cvt_w(const float* __restrict__ Wq,
                                               const float* __restrict__ Wk,
                                               const float* __restrict__ Wv,
                                               f16* __restrict__ Wt) {
    int id = blockIdx.x * 256 + threadIdx.x;
    int w = id >> 18, rem = id & 262143;
    int kk = rem >> 9, n = rem & 511;
    const float* W = (w == 0) ? Wq : (w == 1) ? Wk : Wv;
    Wt[((long)w << 18) + ((long)n << 9) + kk] = (f16)W[((long)kk << 9) + n];
}

// ------------- per-batch transpose: Vt[b][d][s] = V[b*2048+s][d] -------------
__global__ __launch_bounds__(256) void k_transpose_v(const f16* __restrict__ V,
                                                     f16* __restrict__ Vt) {
    __shared__ f16 t[32][33];
    int b = blockIdx.z, s0 = blockIdx.y * 32, d0 = blockIdx.x * 32;
    int x = threadIdx.x & 31, y = threadIdx.x >> 5;
#pragma unroll
    for (int i = 0; i < 4; ++i)
        t[y + i * 8][x] = V[((long)(b * 2048 + s0 + y + i * 8) << 9) + d0 + x];
    __syncthreads();
#pragma unroll
    for (int i = 0; i < 4; ++i)
        Vt[((long)(b * 512 + d0 + y + i * 8) << 11) + s0 + x] = t[x][y + i * 8];
}

// ============ 256x256 GEMM: C = A[M][K] * Bt[N][K]^T ============
// 512 threads = 8 waves (2M x 4N), wave tile 128x64. BK=64; 2 K-tiles (buf0/buf1)/iter.
// LDS per tile-buffer: A halves + B halves, 16KB each (row=128B, swizzle byte^=(r&7)<<4).
// 2 phases per K-tile (MH=0 / MH=1). bf persists across the K-tile; af read-ahead one
// phase early (ping-pong afA/afB). Counted lgkmcnt(8) drains own frags, leaves read-ahead.

#define STAGE8(HBASE, SRC, LD, ROWB, K0)                                                        \
  { const f16* s0_ = (SRC) + ((ROWB) + (tid >> 3)) * (long)(LD) + (K0) + colSw;                 \
    __builtin_amdgcn_global_load_lds(GADDR(s0_), LADDR(smem + (HBASE) + wid * 1024), 16, 0, 0); \
    const f16* s1_ = (SRC) + ((ROWB) + 64 + (tid >> 3)) * (long)(LD) + (K0) + colSw;            \
    __builtin_amdgcn_global_load_lds(GADDR(s1_), LADDR(smem + (HBASE) + 8192 + wid * 1024), 16, 0, 0); }

#define LOAD_AF(AFSET, BUF, MH)                                                      \
  _Pragma("unroll") for (int mi = 0; mi < 4; ++mi) {                                 \
    unsigned ra = wm2 * 64 + mi * 16 + l15;                                          \
    DSRD(AFSET[mi][0], sbase + (BUF) * 65536u + (MH) * 16384u + ra * 128 + cb0);     \
    DSRD(AFSET[mi][1], sbase + (BUF) * 65536u + (MH) * 16384u + ra * 128 + cb1);     \
  }

#define LOAD_BF(BUF)                                                                 \
  _Pragma("unroll") for (int nh = 0; nh < 2; ++nh)                                   \
    _Pragma("unroll") for (int nj = 0; nj < 2; ++nj) {                               \
      unsigned rb = wn2 * 32 + nj * 16 + l15;                                        \
      DSRD(bf[nh][nj][0], sbase + (BUF) * 65536u + 32768u + nh * 16384u + rb * 128 + cb0); \
      DSRD(bf[nh][nj][1], sbase + (BUF) * 65536u + 32768u + nh * 16384u + rb * 128 + cb1); \
    }

#define MFMA_Q(MH, AFSET)                                                            \
  __builtin_amdgcn_sched_barrier(0);                                                 \
  __builtin_amdgcn_s_setprio(1);                                                     \
  _Pragma("unroll") for (int mi = 0; mi < 4; ++mi)                                   \
    _Pragma("unroll") for (int nh = 0; nh < 2; ++nh)                                 \
      _Pragma("unroll") for (int nj = 0; nj < 2; ++nj)                               \
        _Pragma("unroll") for (int ks = 0; ks < 2; ++ks)                             \
          acc[MH][nh][mi][nj] = __builtin_amdgcn_mfma_f32_16x16x32_f16(              \
              AFSET[mi][ks], bf[nh][nj][ks], acc[MH][nh][mi][nj], 0, 0, 0);          \
  __builtin_amdgcn_s_setprio(0);                                                     \
  __builtin_amdgcn_s_barrier();

template <bool OUT_F16, bool QKV>
__global__ __launch_bounds__(512) void k_gemm8(const f16* __restrict__ A,
                                               const f16* __restrict__ Bt,
                                               void* __restrict__ Cv,
                                               void* __restrict__ CvAlt,
                                               const float* __restrict__ b0,
                                               const float* __restrict__ b1,
                                               const float* __restrict__ b2,
                                               int M, int N, int K,
                                               long sA, long sB, long sC) {
    int bxi, byi, bz;
    xcd_remap(bxi, byi, bz);
    A  += bz * sA;
    Bt += bz * sB;
    __shared__ __align__(16) char smem[131072];
    const unsigned sbase = lds_u32(smem);

    const int tid = threadIdx.x;
    const int wid = tid >> 6, lane = tid & 63;
    const int l15 = lane & 15, l4 = lane >> 4;
    const int wm2 = wid >> 2, wn2 = wid & 3;          // wave -> 2x4 grid
    const long rowA0 = (long)byi * 256;
    const long rowB0 = (long)bxi * 256;

    const unsigned sw = (unsigned)((l15 & 7) << 4);
    const unsigned cb0 = (unsigned)(l4 * 16) ^ sw;
    const unsigned cb1 = (unsigned)(64 + l4 * 16) ^ sw;
    const int colSw = (((tid & 7) ^ ((tid >> 3) & 7)) << 3);

    f16x8 afA[4][2], afB[4][2], bf[2][2][2];
    f32x4 acc[2][2][4][2] = {};

    const int NT = K >> 6;                            // K-tiles of 64 (even, >=2)

    // ---- prologue: tile0 all 4 halves -> buf0; tile1 A0,B0 -> buf1 ----
    STAGE8(0,             A,  K, rowA0,       0);
    STAGE8(32768,         Bt, K, rowB0,       0);
    STAGE8(16384,         A,  K, rowA0 + 128, 0);
    STAGE8(32768 + 16384, Bt, K, rowB0 + 128, 0);
    STAGE8(65536,         A,  K, rowA0,       64);
    STAGE8(65536 + 32768, Bt, K, rowB0,       64);
    WAITV4;                                           // t0 complete; t1.A0,B0 in flight
    __builtin_amdgcn_s_barrier();
    LOAD_AF(afA, 0, 0);                               // read-ahead af0(t0)

    for (int t = 0; t < NT; t += 2) {
        const bool more = (t + 2 < NT);
        const int k1 = (t + 1) << 6, k2 = (t + 2) << 6, k3 = (t + 3) << 6;

        // ---- PHa: tile t, MH=0 (uses afA + bf loaded here) ----
        STAGE8(65536 + 16384,         A,  K, rowA0 + 128, k1);   // t1.A1
        STAGE8(65536 + 32768 + 16384, Bt, K, rowB0 + 128, k1);   // t1.B1
        __builtin_amdgcn_s_barrier();
        LOAD_BF(0);                                   // bf(t), 8 reads
        LOAD_AF(afB, 0, 1);                           // read-ahead af1(t), 8 reads
        WAITLG(8);                                    // drain af0(t)+bf(t)
        MFMA_Q(0, afA);

        // ---- PHb: tile t, MH=1 (uses afB + bf) ----
        if (more) { STAGE8(0,     A,  K, rowA0, k2);             // t2.A0
                    STAGE8(32768, Bt, K, rowB0, k2);             // t2.B0
                    WAITV4; }                                    // publish tile t+1
        else      { WAITV0; }
        __builtin_amdgcn_s_barrier();
        LOAD_AF(afA, 1, 0);                           // read-ahead af0(t+1)
        WAITLG(8);                                    // drain af1(t)
        MFMA_Q(1, afB);

        // ---- PHc: tile t+1, MH=0 (uses afA + bf(t+1) loaded here) ----
        if (more) { STAGE8(16384,         A,  K, rowA0 + 128, k2);   // t2.A1
                    STAGE8(32768 + 16384, Bt, K, rowB0 + 128, k2); } // t2.B1
        __builtin_amdgcn_s_barrier();
        LOAD_BF(1);                                   // bf(t+1)
        LOAD_AF(afB, 1, 1);                           // read-ahead af1(t+1)
        WAITLG(8);                                    // drain af0(t+1)+bf(t+1)
        MFMA_Q(0, afA);

        // ---- PHd: tile t+1, MH=1 (uses afB + bf) ----
        if (more) { STAGE8(65536,         A,  K, rowA0, k3);     // t3.A0
                    STAGE8(65536 + 32768, Bt, K, rowB0, k3);     // t3.B0
                    WAITV4; }                                    // publish tile t+2
        else      { WAITV0; }
        __builtin_amdgcn_s_barrier();
        if (more) { LOAD_AF(afA, 0, 0);               // read-ahead af0(t+2)
                    WAITLG(8); }
        else      { WAITLG(0); }
        MFMA_Q(1, afB);
    }

    // ---- epilogue: C/D layout col = lane&15, row = (lane>>4)*4 + reg ----
    const float* bias = nullptr;
    if constexpr (QKV) bias = (bz == 0) ? b0 : (bz == 1) ? b1 : b2;

#pragma unroll
    for (int MH = 0; MH < 2; ++MH)
#pragma unroll
        for (int NH = 0; NH < 2; ++NH)
#pragma unroll
            for (int mi = 0; mi < 4; ++mi)
#pragma unroll
                for (int nj = 0; nj < 2; ++nj) {
                    long gr = rowA0 + MH * 128 + wm2 * 64 + mi * 16 + l4 * 4;
                    int  gc = (int)rowB0 + NH * 128 + wn2 * 32 + nj * 16 + l15;
                    float bv_ = QKV ? bias[gc] : 0.f;
                    if constexpr (OUT_F16) {
                        f16* C;
                        if constexpr (QKV) C = (bz < 2) ? (f16*)Cv + bz * sC : (f16*)CvAlt;
                        else               C = (f16*)Cv + bz * sC;
#pragma unroll
                        for (int r = 0; r < 4; ++r)
                            C[(gr + r) * (long)N + gc] = (f16)(acc[MH][NH][mi][nj][r] + bv_);
                    } else {
                        float* C = (float*)Cv + bz * sC;
#pragma unroll
                        for (int r = 0; r < 4; ++r)
                            C[(gr + r) * (long)N + gc] = acc[MH][NH][mi][nj][r] + bv_;
                    }
                }
}

// ============ PV: 128x128 tile, BK=64, depth-2 counted-vmcnt, swizzled LDS ============
#define PVSTAGE(BUF, K0)                                                                    \
  { _Pragma("unroll") for (int i_ = 0; i_ < 4; ++i_) {                                      \
      const f16* sa_ = A + (rowA0 + i_ * 32 + (tid >> 3)) * (long)K + (K0) + colSw;         \
      __builtin_amdgcn_global_load_lds(GADDR(sa_),                                          \
          LADDR(smem + (BUF) * 32768 + i_ * 4096 + wave * 1024), 16, 0, 0);                 \
      const f16* sb_ = Bt + (rowB0 + i_ * 32 + (tid >> 3)) * (long)K + (K0) + colSw;        \
      __builtin_amdgcn_global_load_lds(GADDR(sb_),                                          \
          LADDR(smem + (BUF) * 32768 + 16384 + i_ * 4096 + wave * 1024), 16, 0, 0);         \
    } }

__global__ __launch_bounds__(256) void k_pv(const f16* __restrict__ Ain,
                                            const f16* __restrict__ Btin,
                                            float* __restrict__ Cout,
                                            int N, int K,
                                            long sA, long sB, long sC) {
    int bxi, byi, bz;
    xcd_remap(bxi, byi, bz);
    const f16* A  = Ain  + bz * sA;
    const f16* Bt = Btin + bz * sB;
    __shared__ __align__(16) char smem[65536];
    const unsigned sbase = lds_u32(smem);

    const int tid = threadIdx.x;
    const int wave = tid >> 6, lane = tid & 63;
    const int l15 = lane & 15, l4 = lane >> 4;
    const int wm = (wave >> 1) * 64, wn = (wave & 1) * 64;
    const long rowA0 = (long)byi * 128;
    const long rowB0 = (long)bxi * 128;

    const unsigned sw = (unsigned)((l15 & 7) << 4);
    const unsigned cb0 = (unsigned)(l4 * 16) ^ sw;
    const unsigned cb1 = (unsigned)(64 + l4 * 16) ^ sw;
    const int colSw = (((tid & 7) ^ ((tid >> 3) & 7)) << 3);

    f32x4 acc[4][4] = {};

    const int nt = K >> 6;
    PVSTAGE(0, 0);
    int cur = 0;
    for (int t = 0; t < nt; ++t) {
        if (t + 1 < nt) { PVSTAGE(cur ^ 1, (t + 1) << 6); WAITV8; }
        else            { WAITV0; }
        __builtin_amdgcn_s_barrier();           // publish tile t

        f16x8 af[4][2], bf[4][2];
        const unsigned aB = sbase + (unsigned)cur * 32768u;
        const unsigned bB = aB + 16384u;
#pragma unroll
        for (int mi = 0; mi < 4; ++mi) {
            unsigned ra = wm + mi * 16 + l15;
            DSRD(af[mi][0], aB + ra * 128 + cb0);
            DSRD(af[mi][1], aB + ra * 128 + cb1);
        }
#pragma unroll
        for (int nj = 0; nj < 4; ++nj) {
            unsigned rb = wn + nj * 16 + l15;
            DSRD(bf[nj][0], bB + rb * 128 + cb0);
            DSRD(bf[nj][1], bB + rb * 128 + cb1);
        }
        WAITLG(0);
        __builtin_amdgcn_sched_barrier(0);
        __builtin_amdgcn_s_setprio(1);
#pragma unroll
        for (int mi = 0; mi < 4; ++mi)
#pragma unroll
            for (int nj = 0; nj < 4; ++nj)
#pragma unroll
                for (int ks = 0; ks < 2; ++ks)
                    acc[mi][nj] = __builtin_amdgcn_mfma_f32_16x16x32_f16(
                        af[mi][ks], bf[nj][ks], acc[mi][nj], 0, 0, 0);
        __builtin_amdgcn_s_setprio(0);
        __builtin_amdgcn_s_barrier();           // all waves done reading buf[cur]
        cur ^= 1;
    }

    float* C = Cout + bz * sC;
#pragma unroll
    for (int mi = 0; mi < 4; ++mi)
#pragma unroll
        for (int nj = 0; nj < 4; ++nj) {
            long gr = rowA0 + wm + mi * 16 + l4 * 4;
            int  gc = (int)rowB0 + wn + nj * 16 + l15;
#pragma unroll
            for (int r = 0; r < 4; ++r)
                C[(gr + r) * (long)N + gc] = acc[mi][nj][r];
        }
}

// ---------------- row softmax in place: fp16 [2048 cols] ----------------
__global__ __launch_bounds__(256) void k_softmax(f16* __restrict__ P) {
    const long row = blockIdx.x;
    f16* p = P + row * 2048;
    const int tid = threadIdx.x, lane = tid & 63, wave = tid >> 6;

    f16x8 v = ((const f16x8*)p)[tid];
    float f[8];
#pragma unroll
    for (int j = 0; j < 8; ++j) f[j] = (float)v[j];
    float m = fmaxf(fmaxf(fmaxf(f[0], f[1]), fmaxf(f[2], f[3])),
                    fmaxf(fmaxf(f[4], f[5]), fmaxf(f[6], f[7])));
#pragma unroll
    for (int off = 32; off; off >>= 1) m = fmaxf(m, __shfl_xor(m, off));

    __shared__ float red[4];
    __shared__ float bc[2];
    if (lane == 0) red[wave] = m;
    __syncthreads();
    if (tid == 0) bc[0] = fmaxf(fmaxf(red[0], red[1]), fmaxf(red[2], red[3]));
    __syncthreads();
    m = bc[0];

    float e[8], sum = 0.f;
#pragma unroll
    for (int j = 0; j < 8; ++j) { e[j] = __expf(f[j] - m); sum += e[j]; }
#pragma unroll
    for (int off = 32; off; off >>= 1) sum += __shfl_xor(sum, off);
    if (lane == 0) red[wave] = sum;
    __syncthreads();
    if (tid == 0) bc[1] = (red[0] + red[1]) + (red[2] + red[3]);
    __syncthreads();
    float inv = 1.f / bc[1];

    f16x8 o;
#pragma unroll
    for (int j = 0; j < 8; ++j) o[j] = (f16)(e[j] * inv);
    ((f16x8*)p)[tid] = o;
}

extern "C" void kernel_launch(void* const* d_in, const int* in_sizes, int n_in,
                              void* d_out, int out_size, void* d_ws, size_t ws_size,
                              hipStream_t stream) {
    const float* x  = (const float*)d_in[0];
    const float* Wq = (const float*)d_in[1];
    const float* bq = (const float*)d_in[2];
    const float* Wk = (const float*)d_in[3];
    const float* bk = (const float*)d_in[4];
    const float* Wv = (const float*)d_in[5];
    const float* bv = (const float*)d_in[6];
    float* out = (float*)d_out;

    // ---- workspace layout (96 MiB peak, phase-aliased) ----
    char* ws = (char*)d_ws;
    f16* qh = (f16*)(ws + 0);                  // [16384][512] fp16 (dead after scores)
    f16* kh = (f16*)(ws + 16777216);           // [16384][512]
    f16* P8 = (f16*)(ws + 33554432);           // [8][2048][2048] fp16 scores -> probs
    f16* Wt = (f16*)(ws + 33554432);           // [3][512][512] (aliases P8; dead after proj)
    f16* vt = (f16*)(ws + 0);                  // [8][512][2048] (aliases qh; written after scores)
    f16* xh = (f16*)d_out;                     // [16384][512] fp16 (d_out as scratch)
    f16* vv = (f16*)((char*)d_out + 16777216); // [16384][512] fp16

    k_cvt_x<<<8192, 256, 0, stream>>>(x, xh);
    k_cvt_w<<<3072, 256, 0, stream>>>(Wq, Wk, Wv, Wt);

    // QKV projections: z=3, M=16384, N=512, K=512  (384 blocks, %8==0)
    k_gemm8<true, true><<<dim3(2, 64, 3), 512, 0, stream>>>(
        xh, Wt, qh, vv, bq, bk, bv, 16384, 512, 512,
        0, (long)512 * 512, (long)16384 * 512);

    // scores: S[b] = q[b] k[b]^T, z=8, fp16 out  (512 blocks)
    k_gemm8<true, false><<<dim3(8, 8, 8), 512, 0, stream>>>(
        qh, kh, P8, nullptr, nullptr, nullptr, nullptr, 2048, 2048, 512,
        (long)2048 * 512, (long)2048 * 512, (long)2048 * 2048);

    // transpose v (qh region dead now; vt aliases it)
    k_transpose_v<<<dim3(16, 64, 8), 256, 0, stream>>>(vv, vt);

    // softmax in place on all 16384 rows
    k_softmax<<<16384, 256, 0, stream>>>(P8);

    // out[b] = P[b] v[b], z=8, fp32 out (512 blocks)
    k_pv<<<dim3(4, 16, 8), 256, 0, stream>>>(
        P8, vt, out, 512, 2048,
        (long)2048 * 2048, (long)512 * 2048, (long)2048 * 512);
}

// Round 7
// 184.909 us; speedup vs baseline: 1.6180x; 1.6180x over previous
//
#include <hip/hip_runtime.h>
#include <hip/hip_fp16.h>

// WordAttention on MI355X: fp16 MFMA pipeline.
//   q,k,v = x@W + b (fp16);  S = q k^T (fp16, z=8);  P = softmax(S) in-place;  out = P v (fp32, z=8)
// proj + scores: 256x256 8-phase counted-vmcnt GEMM (R5 skeleton) + quadrant-persistent
//   fragments: af reloaded per MH-half (8 reads), bf loaded once per K-tile (2x4 reads),
//   24 ds_read_b128 per K-tile per wave (was 48). All waits plain lgkmcnt(0).
// PV: 128x128 BK=64 depth-2 counted-vmcnt pipeline, swizzled LDS, asm reads.
// All GEMM grids XCD-swizzled (T1) for L2 locality.

typedef _Float16 f16;
typedef __attribute__((ext_vector_type(8))) _Float16 f16x8;
typedef __attribute__((ext_vector_type(4))) _Float16 f16x4;
typedef __attribute__((ext_vector_type(4))) float f32x4;
typedef __attribute__((address_space(3))) char lds_t;

#define GADDR(p) ((const __attribute__((address_space(1))) void*)(p))
#define LADDR(p) ((__attribute__((address_space(3))) void*)(p))

__device__ __forceinline__ unsigned lds_u32(void* p) {
    return (unsigned)(unsigned long long)(lds_t*)p;
}

// asm ds_read_b128: opaque to alias analysis; caller provides lgkmcnt waits.
#define DSRD(dst, a) asm volatile("ds_read_b128 %0, %1" : "=v"(dst) : "v"(a))
#define WAITV0 asm volatile("s_waitcnt vmcnt(0)" ::: "memory")
#define WAITV4 asm volatile("s_waitcnt vmcnt(4)" ::: "memory")
#define WAITV8 asm volatile("s_waitcnt vmcnt(8)" ::: "memory")
#define WAITLG0 asm volatile("s_waitcnt lgkmcnt(0)" ::: "memory")

// T1: XCD-aware bijective remap (requires nwg % 8 == 0; all our grids satisfy).
__device__ __forceinline__ void xcd_remap(int& bx, int& by, int& bz) {
    const int gx = gridDim.x, gy = gridDim.y;
    const int nwg = gx * gy * gridDim.z;
    const int f = (blockIdx.z * gy + blockIdx.y) * gx + blockIdx.x;
    int L = (f & 7) * (nwg >> 3) + (f >> 3);
    bx = L % gx; int r = L / gx; by = r % gy; bz = r / gy;
}

// ---------------- convert x: fp32 -> fp16 ----------------
__global__ __launch_bounds__(256) void k_cvt_x(const float* __restrict__ in,
                                               f16* __restrict__ out) {
    long i = (long)blockIdx.x * 256 + threadIdx.x;
    float4 v = ((const float4*)in)[i];
    f16x4 h = { (f16)v.x, (f16)v.y, (f16)v.z, (f16)v.w };
    ((f16x4*)out)[i] = h;
}

// ------------- convert+transpose weights: Wt[w][n][k] = W[w][k][n] -------------
__global__ __launch_bounds__(256) void k_cvt_w(const float* __restrict__ Wq,
                                               const float* __restrict__ Wk,
                                               const float* __restrict__ Wv,
                                               f16* __restrict__ Wt) {
    int id = blockIdx.x * 256 + threadIdx.x;
    int w = id >> 18, rem = id & 262143;
    int kk = rem >> 9, n = rem & 511;
    const float* W = (w == 0) ? Wq : (w == 1) ? Wk : Wv;
    Wt[((long)w << 18) + ((long)n << 9) + kk] = (f16)W[((long)kk << 9) + n];
}

// ------------- per-batch transpose: Vt[b][d][s] = V[b*2048+s][d] -------------
__global__ __launch_bounds__(256) void k_transpose_v(const f16* __restrict__ V,
                                                     f16* __restrict__ Vt) {
    __shared__ f16 t[32][33];
    int b = blockIdx.z, s0 = blockIdx.y * 32, d0 = blockIdx.x * 32;
    int x = threadIdx.x & 31, y = threadIdx.x >> 5;
#pragma unroll
    for (int i = 0; i < 4; ++i)
        t[y + i * 8][x] = V[((long)(b * 2048 + s0 + y + i * 8) << 9) + d0 + x];
    __syncthreads();
#pragma unroll
    for (int i = 0; i < 4; ++i)
        Vt[((long)(b * 512 + d0 + y + i * 8) << 11) + s0 + x] = t[x][y + i * 8];
}

// ============ 256x256 GEMM: C = A[M][K] * Bt[N][K]^T ============
// 512 threads = 8 waves (2M x 4N), wave tile 128x64. BK=64; 2 K-tiles (buf0/buf1)/iter.
// LDS per tile-buffer: A halves + B halves, 16KB each (row=128B, swizzle byte^=(r&7)<<4).
// 4 quadrant phases per K-tile, order (0,0)(0,1)(1,0)(1,1); af per MH, bf per K-tile.

#define STAGE8(HBASE, SRC, LD, ROWB, K0)                                                        \
  { const f16* s0_ = (SRC) + ((ROWB) + (tid >> 3)) * (long)(LD) + (K0) + colSw;                 \
    __builtin_amdgcn_global_load_lds(GADDR(s0_), LADDR(smem + (HBASE) + wid * 1024), 16, 0, 0); \
    const f16* s1_ = (SRC) + ((ROWB) + 64 + (tid >> 3)) * (long)(LD) + (K0) + colSw;            \
    __builtin_amdgcn_global_load_lds(GADDR(s1_), LADDR(smem + (HBASE) + 8192 + wid * 1024), 16, 0, 0); }

#define LOAD_AF(AFSET, BUF, MH)                                                      \
  _Pragma("unroll") for (int mi = 0; mi < 4; ++mi) {                                 \
    unsigned ra = wm2 * 64 + mi * 16 + l15;                                          \
    DSRD(AFSET[mi][0], sbase + (BUF) * 65536u + (MH) * 16384u + ra * 128 + cb0);     \
    DSRD(AFSET[mi][1], sbase + (BUF) * 65536u + (MH) * 16384u + ra * 128 + cb1);     \
  }

#define LOAD_BFS(NH, BUF)                                                                  \
  _Pragma("unroll") for (int nj = 0; nj < 2; ++nj) {                                       \
    unsigned rb = wn2 * 32 + nj * 16 + l15;                                                \
    DSRD(bf[NH][nj][0], sbase + (BUF) * 65536u + 32768u + (NH) * 16384u + rb * 128 + cb0); \
    DSRD(bf[NH][nj][1], sbase + (BUF) * 65536u + 32768u + (NH) * 16384u + rb * 128 + cb1); \
  }

#define PHASEQ(MH, NH, AFSET, READ_CODE, STAGE_CODE, WAIT_CODE)                      \
  {                                                                                  \
    READ_CODE;                                                                       \
    STAGE_CODE;                                                                      \
    WAIT_CODE;                                                                       \
    __builtin_amdgcn_s_barrier();                                                    \
    WAITLG0;                                                                         \
    __builtin_amdgcn_sched_barrier(0);                                               \
    __builtin_amdgcn_s_setprio(1);                                                   \
    _Pragma("unroll") for (int mi = 0; mi < 4; ++mi)                                 \
      _Pragma("unroll") for (int nj = 0; nj < 2; ++nj)                               \
        _Pragma("unroll") for (int ks = 0; ks < 2; ++ks)                             \
          acc[MH][NH][mi][nj] = __builtin_amdgcn_mfma_f32_16x16x32_f16(              \
              AFSET[mi][ks], bf[NH][nj][ks], acc[MH][NH][mi][nj], 0, 0, 0);          \
    __builtin_amdgcn_s_setprio(0);                                                   \
    __builtin_amdgcn_s_barrier();                                                    \
  }

template <bool OUT_F16, bool QKV>
__global__ __launch_bounds__(512) void k_gemm8(const f16* __restrict__ A,
                                               const f16* __restrict__ Bt,
                                               void* __restrict__ Cv,
                                               void* __restrict__ CvAlt,
                                               const float* __restrict__ b0,
                                               const float* __restrict__ b1,
                                               const float* __restrict__ b2,
                                               int M, int N, int K,
                                               long sA, long sB, long sC) {
    int bxi, byi, bz;
    xcd_remap(bxi, byi, bz);
    A  += bz * sA;
    Bt += bz * sB;
    __shared__ __align__(16) char smem[131072];
    const unsigned sbase = lds_u32(smem);

    const int tid = threadIdx.x;
    const int wid = tid >> 6, lane = tid & 63;
    const int l15 = lane & 15, l4 = lane >> 4;
    const int wm2 = wid >> 2, wn2 = wid & 3;          // wave -> 2x4 grid
    const long rowA0 = (long)byi * 256;
    const long rowB0 = (long)bxi * 256;

    const unsigned sw = (unsigned)((l15 & 7) << 4);
    const unsigned cb0 = (unsigned)(l4 * 16) ^ sw;
    const unsigned cb1 = (unsigned)(64 + l4 * 16) ^ sw;
    const int colSw = (((tid & 7) ^ ((tid >> 3) & 7)) << 3);

    f16x8 af0[4][2], af1[4][2], bf[2][2][2];
    f32x4 acc[2][2][4][2] = {};

    const int NT = K >> 6;                            // K-tiles of 64 (even, >=2)

    // ---- prologue: tile0 all 4 halves -> buf0; tile1 A0,B0 -> buf1 ----
    STAGE8(0,             A,  K, rowA0,       0);
    STAGE8(32768,         Bt, K, rowB0,       0);
    STAGE8(16384,         A,  K, rowA0 + 128, 0);
    STAGE8(32768 + 16384, Bt, K, rowB0 + 128, 0);
    STAGE8(65536,         A,  K, rowA0,       64);
    STAGE8(65536 + 32768, Bt, K, rowB0,       64);
    WAITV4;                                           // t0 complete; t1.A0,B0 in flight
    __builtin_amdgcn_s_barrier();

    for (int t = 0; t < NT; t += 2) {
        const bool more = (t + 2 < NT);
        const int k1 = (t + 1) << 6, k2 = (t + 2) << 6, k3 = (t + 3) << 6;

        // ---- tile t (buf0): phases (0,0)(0,1)(1,0)(1,1) ----
        PHASEQ(0, 0, af0, { LOAD_AF(af0, 0, 0); LOAD_BFS(0, 0); },
               { STAGE8(65536 + 16384,         A,  K, rowA0 + 128, k1); }, );
        PHASEQ(0, 1, af0, { LOAD_BFS(1, 0); },
               { STAGE8(65536 + 32768 + 16384, Bt, K, rowB0 + 128, k1); }, );
        PHASEQ(1, 0, af1, { LOAD_AF(af1, 0, 1); },
               { if (more) STAGE8(0,             A,  K, rowA0,       k2); }, );
        PHASEQ(1, 1, af1, { },
               { if (more) STAGE8(32768,         Bt, K, rowB0,       k2); },
               { if (more) WAITV4; else WAITV0; });

        // ---- tile t+1 (buf1) ----
        PHASEQ(0, 0, af0, { LOAD_AF(af0, 1, 0); LOAD_BFS(0, 1); },
               { if (more) STAGE8(16384,         A,  K, rowA0 + 128, k2); }, );
        PHASEQ(0, 1, af0, { LOAD_BFS(1, 1); },
               { if (more) STAGE8(32768 + 16384, Bt, K, rowB0 + 128, k2); }, );
        PHASEQ(1, 0, af1, { LOAD_AF(af1, 1, 1); },
               { if (more) STAGE8(65536,         A,  K, rowA0,       k3); }, );
        PHASEQ(1, 1, af1, { },
               { if (more) STAGE8(65536 + 32768, Bt, K, rowB0,       k3); },
               { if (more) WAITV4; else WAITV0; });
    }

    // ---- epilogue: C/D layout col = lane&15, row = (lane>>4)*4 + reg ----
    const float* bias = nullptr;
    if constexpr (QKV) bias = (bz == 0) ? b0 : (bz == 1) ? b1 : b2;

#pragma unroll
    for (int MH = 0; MH < 2; ++MH)
#pragma unroll
        for (int NH = 0; NH < 2; ++NH)
#pragma unroll
            for (int mi = 0; mi < 4; ++mi)
#pragma unroll
                for (int nj = 0; nj < 2; ++nj) {
                    long gr = rowA0 + MH * 128 + wm2 * 64 + mi * 16 + l4 * 4;
                    int  gc = (int)rowB0 + NH * 128 + wn2 * 32 + nj * 16 + l15;
                    float bv_ = QKV ? bias[gc] : 0.f;
                    if constexpr (OUT_F16) {
                        f16* C;
                        if constexpr (QKV) C = (bz < 2) ? (f16*)Cv + bz * sC : (f16*)CvAlt;
                        else               C = (f16*)Cv + bz * sC;
#pragma unroll
                        for (int r = 0; r < 4; ++r)
                            C[(gr + r) * (long)N + gc] = (f16)(acc[MH][NH][mi][nj][r] + bv_);
                    } else {
                        float* C = (float*)Cv + bz * sC;
#pragma unroll
                        for (int r = 0; r < 4; ++r)
                            C[(gr + r) * (long)N + gc] = acc[MH][NH][mi][nj][r] + bv_;
                    }
                }
}

// ============ PV: 128x128 tile, BK=64, depth-2 counted-vmcnt, swizzled LDS ============
#define PVSTAGE(BUF, K0)                                                                    \
  { _Pragma("unroll") for (int i_ = 0; i_ < 4; ++i_) {                                      \
      const f16* sa_ = A + (rowA0 + i_ * 32 + (tid >> 3)) * (long)K + (K0) + colSw;         \
      __builtin_amdgcn_global_load_lds(GADDR(sa_),                                          \
          LADDR(smem + (BUF) * 32768 + i_ * 4096 + wave * 1024), 16, 0, 0);                 \
      const f16* sb_ = Bt + (rowB0 + i_ * 32 + (tid >> 3)) * (long)K + (K0) + colSw;        \
      __builtin_amdgcn_global_load_lds(GADDR(sb_),                                          \
          LADDR(smem + (BUF) * 32768 + 16384 + i_ * 4096 + wave * 1024), 16, 0, 0);         \
    } }

__global__ __launch_bounds__(256) void k_pv(const f16* __restrict__ Ain,
                                            const f16* __restrict__ Btin,
                                            float* __restrict__ Cout,
                                            int N, int K,
                                            long sA, long sB, long sC) {
    int bxi, byi, bz;
    xcd_remap(bxi, byi, bz);
    const f16* A  = Ain  + bz * sA;
    const f16* Bt = Btin + bz * sB;
    __shared__ __align__(16) char smem[65536];
    const unsigned sbase = lds_u32(smem);

    const int tid = threadIdx.x;
    const int wave = tid >> 6, lane = tid & 63;
    const int l15 = lane & 15, l4 = lane >> 4;
    const int wm = (wave >> 1) * 64, wn = (wave & 1) * 64;
    const long rowA0 = (long)byi * 128;
    const long rowB0 = (long)bxi * 128;

    const unsigned sw = (unsigned)((l15 & 7) << 4);
    const unsigned cb0 = (unsigned)(l4 * 16) ^ sw;
    const unsigned cb1 = (unsigned)(64 + l4 * 16) ^ sw;
    const int colSw = (((tid & 7) ^ ((tid >> 3) & 7)) << 3);

    f32x4 acc[4][4] = {};

    const int nt = K >> 6;
    PVSTAGE(0, 0);
    int cur = 0;
    for (int t = 0; t < nt; ++t) {
        if (t + 1 < nt) { PVSTAGE(cur ^ 1, (t + 1) << 6); WAITV8; }
        else            { WAITV0; }
        __builtin_amdgcn_s_barrier();           // publish tile t

        f16x8 af[4][2], bf[4][2];
        const unsigned aB = sbase + (unsigned)cur * 32768u;
        const unsigned bB = aB + 16384u;
#pragma unroll
        for (int mi = 0; mi < 4; ++mi) {
            unsigned ra = wm + mi * 16 + l15;
            DSRD(af[mi][0], aB + ra * 128 + cb0);
            DSRD(af[mi][1], aB + ra * 128 + cb1);
        }
#pragma unroll
        for (int nj = 0; nj < 4; ++nj) {
            unsigned rb = wn + nj * 16 + l15;
            DSRD(bf[nj][0], bB + rb * 128 + cb0);
            DSRD(bf[nj][1], bB + rb * 128 + cb1);
        }
        WAITLG0;
        __builtin_amdgcn_sched_barrier(0);
        __builtin_amdgcn_s_setprio(1);
#pragma unroll
        for (int mi = 0; mi < 4; ++mi)
#pragma unroll
            for (int nj = 0; nj < 4; ++nj)
#pragma unroll
                for (int ks = 0; ks < 2; ++ks)
                    acc[mi][nj] = __builtin_amdgcn_mfma_f32_16x16x32_f16(
                        af[mi][ks], bf[nj][ks], acc[mi][nj], 0, 0, 0);
        __builtin_amdgcn_s_setprio(0);
        __builtin_amdgcn_s_barrier();           // all waves done reading buf[cur]
        cur ^= 1;
    }

    float* C = Cout + bz * sC;
#pragma unroll
    for (int mi = 0; mi < 4; ++mi)
#pragma unroll
        for (int nj = 0; nj < 4; ++nj) {
            long gr = rowA0 + wm + mi * 16 + l4 * 4;
            int  gc = (int)rowB0 + wn + nj * 16 + l15;
#pragma unroll
            for (int r = 0; r < 4; ++r)
                C[(gr + r) * (long)N + gc] = acc[mi][nj][r];
        }
}

// ---------------- row softmax in place: fp16 [2048 cols] ----------------
__global__ __launch_bounds__(256) void k_softmax(f16* __restrict__ P) {
    const long row = blockIdx.x;
    f16* p = P + row * 2048;
    const int tid = threadIdx.x, lane = tid & 63, wave = tid >> 6;

    f16x8 v = ((const f16x8*)p)[tid];
    float f[8];
#pragma unroll
    for (int j = 0; j < 8; ++j) f[j] = (float)v[j];
    float m = fmaxf(fmaxf(fmaxf(f[0], f[1]), fmaxf(f[2], f[3])),
                    fmaxf(fmaxf(f[4], f[5]), fmaxf(f[6], f[7])));
#pragma unroll
    for (int off = 32; off; off >>= 1) m = fmaxf(m, __shfl_xor(m, off));

    __shared__ float red[4];
    __shared__ float bc[2];
    if (lane == 0) red[wave] = m;
    __syncthreads();
    if (tid == 0) bc[0] = fmaxf(fmaxf(red[0], red[1]), fmaxf(red[2], red[3]));
    __syncthreads();
    m = bc[0];

    float e[8], sum = 0.f;
#pragma unroll
    for (int j = 0; j < 8; ++j) { e[j] = __expf(f[j] - m); sum += e[j]; }
#pragma unroll
    for (int off = 32; off; off >>= 1) sum += __shfl_xor(sum, off);
    if (lane == 0) red[wave] = sum;
    __syncthreads();
    if (tid == 0) bc[1] = (red[0] + red[1]) + (red[2] + red[3]);
    __syncthreads();
    float inv = 1.f / bc[1];

    f16x8 o;
#pragma unroll
    for (int j = 0; j < 8; ++j) o[j] = (f16)(e[j] * inv);
    ((f16x8*)p)[tid] = o;
}

extern "C" void kernel_launch(void* const* d_in, const int* in_sizes, int n_in,
                              void* d_out, int out_size, void* d_ws, size_t ws_size,
                              hipStream_t stream) {
    const float* x  = (const float*)d_in[0];
    const float* Wq = (const float*)d_in[1];
    const float* bq = (const float*)d_in[2];
    const float* Wk = (const float*)d_in[3];
    const float* bk = (const float*)d_in[4];
    const float* Wv = (const float*)d_in[5];
    const float* bv = (const float*)d_in[6];
    float* out = (float*)d_out;

    // ---- workspace layout (96 MiB peak, phase-aliased) ----
    char* ws = (char*)d_ws;
    f16* qh = (f16*)(ws + 0);                  // [16384][512] fp16 (dead after scores)
    f16* kh = (f16*)(ws + 16777216);           // [16384][512]
    f16* P8 = (f16*)(ws + 33554432);           // [8][2048][2048] fp16 scores -> probs
    f16* Wt = (f16*)(ws + 33554432);           // [3][512][512] (aliases P8; dead after proj)
    f16* vt = (f16*)(ws + 0);                  // [8][512][2048] (aliases qh; written after scores)
    f16* xh = (f16*)d_out;                     // [16384][512] fp16 (d_out as scratch)
    f16* vv = (f16*)((char*)d_out + 16777216); // [16384][512] fp16

    k_cvt_x<<<8192, 256, 0, stream>>>(x, xh);
    k_cvt_w<<<3072, 256, 0, stream>>>(Wq, Wk, Wv, Wt);

    // QKV projections: z=3, M=16384, N=512, K=512  (384 blocks, %8==0)
    k_gemm8<true, true><<<dim3(2, 64, 3), 512, 0, stream>>>(
        xh, Wt, qh, vv, bq, bk, bv, 16384, 512, 512,
        0, (long)512 * 512, (long)16384 * 512);

    // scores: S[b] = q[b] k[b]^T, z=8, fp16 out  (512 blocks)
    k_gemm8<true, false><<<dim3(8, 8, 8), 512, 0, stream>>>(
        qh, kh, P8, nullptr, nullptr, nullptr, nullptr, 2048, 2048, 512,
        (long)2048 * 512, (long)2048 * 512, (long)2048 * 2048);

    // transpose v (qh region dead now; vt aliases it)
    k_transpose_v<<<dim3(16, 64, 8), 256, 0, stream>>>(vv, vt);

    // softmax in place on all 16384 rows
    k_softmax<<<16384, 256, 0, stream>>>(P8);

    // out[b] = P[b] v[b], z=8, fp32 out (512 blocks)
    k_pv<<<dim3(4, 16, 8), 256, 0, stream>>>(
        P8, vt, out, 512, 2048,
        (long)2048 * 2048, (long)512 * 2048, (long)2048 * 512);
}

// Round 8
// 171.594 us; speedup vs baseline: 1.7436x; 1.0776x over previous
//
#include <hip/hip_runtime.h>
#include <hip/hip_fp16.h>

// WordAttention on MI355X: fp16 MFMA pipeline.
//   q,k,v = x@W + b (fp16);  S = q k^T (fp16, z=8);  P = softmax(S) in-place;  out = P v (fp32, z=8)
// proj + scores: 256x256 8-phase counted-vmcnt GEMM (R5 skeleton, proven best).
//   proj bz==2 writes v TRANSPOSED (vt[b][d][s]) via f16x4 stores -> no transpose kernel.
// PV: 128x128 BK=64 depth-2 counted-vmcnt pipeline, swizzled LDS, asm reads.
// All GEMM grids XCD-swizzled (T1) for L2 locality.
//
// Memory plan (96 MiB ws + d_out as scratch):
//   ws:   vt[0,32M)  xh[32M,48M)+Wt[48M,50M)  P8[32M,96M) (P8 overwrites dead xh/Wt)
//   d_out: qh[0,16M) kh[16M,32M) during proj/scores; PV output overwrites (qh/kh dead).

typedef _Float16 f16;
typedef __attribute__((ext_vector_type(8))) _Float16 f16x8;
typedef __attribute__((ext_vector_type(4))) _Float16 f16x4;
typedef __attribute__((ext_vector_type(4))) float f32x4;
typedef __attribute__((address_space(3))) char lds_t;

#define GADDR(p) ((const __attribute__((address_space(1))) void*)(p))
#define LADDR(p) ((__attribute__((address_space(3))) void*)(p))

__device__ __forceinline__ unsigned lds_u32(void* p) {
    return (unsigned)(unsigned long long)(lds_t*)p;
}

// asm ds_read_b128: opaque to alias analysis; caller provides lgkmcnt waits.
#define DSRD(dst, a) asm volatile("ds_read_b128 %0, %1" : "=v"(dst) : "v"(a))
#define WAITV0 asm volatile("s_waitcnt vmcnt(0)" ::: "memory")
#define WAITV4 asm volatile("s_waitcnt vmcnt(4)" ::: "memory")
#define WAITV8 asm volatile("s_waitcnt vmcnt(8)" ::: "memory")
#define WAITLG0 asm volatile("s_waitcnt lgkmcnt(0)" ::: "memory")

// T1: XCD-aware bijective remap (requires nwg % 8 == 0; all our grids satisfy).
__device__ __forceinline__ void xcd_remap(int& bx, int& by, int& bz) {
    const int gx = gridDim.x, gy = gridDim.y;
    const int nwg = gx * gy * gridDim.z;
    const int f = (blockIdx.z * gy + blockIdx.y) * gx + blockIdx.x;
    int L = (f & 7) * (nwg >> 3) + (f >> 3);
    bx = L % gx; int r = L / gx; by = r % gy; bz = r / gy;
}

// ---------------- convert x: fp32 -> fp16 ----------------
__global__ __launch_bounds__(256) void k_cvt_x(const float* __restrict__ in,
                                               f16* __restrict__ out) {
    long i = (long)blockIdx.x * 256 + threadIdx.x;
    float4 v = ((const float4*)in)[i];
    f16x4 h = { (f16)v.x, (f16)v.y, (f16)v.z, (f16)v.w };
    ((f16x4*)out)[i] = h;
}

// ------------- convert+transpose weights: Wt[w][n][k] = W[w][k][n] -------------
__global__ __launch_bounds__(256) void k_cvt_w(const float* __restrict__ Wq,
                                               const float* __restrict__ Wk,
                                               const float* __restrict__ Wv,
                                               f16* __restrict__ Wt) {
    int id = blockIdx.x * 256 + threadIdx.x;
    int w = id >> 18, rem = id & 262143;
    int kk = rem >> 9, n = rem & 511;
    const float* W = (w == 0) ? Wq : (w == 1) ? Wk : Wv;
    Wt[((long)w << 18) + ((long)n << 9) + kk] = (f16)W[((long)kk << 9) + n];
}

// ============ 256x256 8-phase GEMM: C = A[M][K] * Bt[N][K]^T ============
// 512 threads = 8 waves (2M x 4N). BK=64; 2 K-tiles (buf0/buf1) per loop iteration.
// LDS per tile-buffer: A halves + B halves, 16KB each (row=128B, swizzle byte^=(r&7)<<4).
// Counted vmcnt(4) at P4/P8 only; tail drains vmcnt(0). [R5-proven schedule]

#define STAGE8(HBASE, SRC, LD, ROWB, K0)                                                        \
  { const f16* s0_ = (SRC) + ((ROWB) + (tid >> 3)) * (long)(LD) + (K0) + colSw;                 \
    __builtin_amdgcn_global_load_lds(GADDR(s0_), LADDR(smem + (HBASE) + wid * 1024), 16, 0, 0); \
    const f16* s1_ = (SRC) + ((ROWB) + 64 + (tid >> 3)) * (long)(LD) + (K0) + colSw;            \
    __builtin_amdgcn_global_load_lds(GADDR(s1_), LADDR(smem + (HBASE) + 8192 + wid * 1024), 16, 0, 0); }

#define PHASE8(BUF, MH, NH, STAGE_CODE, WAIT_CODE)                                   \
  {                                                                                  \
    f16x8 af[4][2], bf[2][2];                                                        \
    const unsigned aB = sbase + (BUF) * 65536u + (MH) * 16384u;                      \
    const unsigned bB = sbase + (BUF) * 65536u + 32768u + (NH) * 16384u;             \
    _Pragma("unroll") for (int mi = 0; mi < 4; ++mi) {                               \
      unsigned ra = wm2 * 64 + mi * 16 + l15;                                        \
      DSRD(af[mi][0], aB + ra * 128 + cb0);                                          \
      DSRD(af[mi][1], aB + ra * 128 + cb1);                                          \
    }                                                                                \
    _Pragma("unroll") for (int nj = 0; nj < 2; ++nj) {                               \
      unsigned rb = wn2 * 32 + nj * 16 + l15;                                        \
      DSRD(bf[nj][0], bB + rb * 128 + cb0);                                          \
      DSRD(bf[nj][1], bB + rb * 128 + cb1);                                          \
    }                                                                                \
    STAGE_CODE;                                                                      \
    WAIT_CODE;                                                                       \
    __builtin_amdgcn_s_barrier();                                                    \
    WAITLG0;                                                                         \
    __builtin_amdgcn_sched_barrier(0);                                               \
    __builtin_amdgcn_s_setprio(1);                                                   \
    _Pragma("unroll") for (int mi = 0; mi < 4; ++mi)                                 \
      _Pragma("unroll") for (int nj = 0; nj < 2; ++nj)                               \
        _Pragma("unroll") for (int ks = 0; ks < 2; ++ks)                             \
          acc[MH][NH][mi][nj] = __builtin_amdgcn_mfma_f32_16x16x32_f16(              \
              af[mi][ks], bf[nj][ks], acc[MH][NH][mi][nj], 0, 0, 0);                 \
    __builtin_amdgcn_s_setprio(0);                                                   \
    __builtin_amdgcn_s_barrier();                                                    \
  }

template <bool OUT_F16, bool QKV>
__global__ __launch_bounds__(512) void k_gemm8(const f16* __restrict__ A,
                                               const f16* __restrict__ Bt,
                                               void* __restrict__ Cv,
                                               void* __restrict__ CvAlt,
                                               const float* __restrict__ b0,
                                               const float* __restrict__ b1,
                                               const float* __restrict__ b2,
                                               int M, int N, int K,
                                               long sA, long sB, long sC) {
    int bxi, byi, bz;
    xcd_remap(bxi, byi, bz);
    A  += bz * sA;
    Bt += bz * sB;
    __shared__ __align__(16) char smem[131072];
    const unsigned sbase = lds_u32(smem);

    const int tid = threadIdx.x;
    const int wid = tid >> 6, lane = tid & 63;
    const int l15 = lane & 15, l4 = lane >> 4;
    const int wm2 = wid >> 2, wn2 = wid & 3;          // wave -> 2x4 grid
    const long rowA0 = (long)byi * 256;
    const long rowB0 = (long)bxi * 256;

    const unsigned sw = (unsigned)((l15 & 7) << 4);
    const unsigned cb0 = (unsigned)(l4 * 16) ^ sw;
    const unsigned cb1 = (unsigned)(64 + l4 * 16) ^ sw;
    const int colSw = (((tid & 7) ^ ((tid >> 3) & 7)) << 3);

    f32x4 acc[2][2][4][2] = {};

    const int NT = K >> 6;                            // K-tiles of 64 (even, >=2)

    // ---- prologue: tile0 all 4 halves -> buf0; tile1 A0,B0 -> buf1 ----
    STAGE8(0,             A,  K, rowA0,       0);
    STAGE8(32768,         Bt, K, rowB0,       0);
    STAGE8(16384,         A,  K, rowA0 + 128, 0);
    STAGE8(32768 + 16384, Bt, K, rowB0 + 128, 0);
    STAGE8(65536,         A,  K, rowA0,       64);
    STAGE8(65536 + 32768, Bt, K, rowB0,       64);
    WAITV4;                                           // t0 complete; t1.A0,B0 in flight
    __builtin_amdgcn_s_barrier();

    for (int t = 0; t < NT; t += 2) {
        const bool more = (t + 2 < NT);
        const int k1 = (t + 1) << 6, k2 = (t + 2) << 6, k3 = (t + 3) << 6;
        PHASE8(0, 0, 0, { STAGE8(65536 + 16384,         A,  K, rowA0 + 128, k1); }, );
        PHASE8(0, 0, 1, { STAGE8(65536 + 32768 + 16384, Bt, K, rowB0 + 128, k1); }, );
        PHASE8(0, 1, 0, { if (more) STAGE8(0,             A,  K, rowA0,       k2); }, );
        PHASE8(0, 1, 1, { if (more) STAGE8(32768,         Bt, K, rowB0,       k2); },
                        { if (more) WAITV4; else WAITV0; });
        PHASE8(1, 0, 0, { if (more) STAGE8(16384,         A,  K, rowA0 + 128, k2); }, );
        PHASE8(1, 0, 1, { if (more) STAGE8(32768 + 16384, Bt, K, rowB0 + 128, k2); }, );
        PHASE8(1, 1, 0, { if (more) STAGE8(65536,         A,  K, rowA0,       k3); }, );
        PHASE8(1, 1, 1, { if (more) STAGE8(65536 + 32768, Bt, K, rowB0,       k3); },
                        { if (more) WAITV4; else WAITV0; });
    }

    // ---- epilogue: C/D layout col = lane&15, row = (lane>>4)*4 + reg ----
    if constexpr (QKV) {
        if (bz == 2) {
            // v path: write TRANSPOSED vt[b][d][sLocal] = acc + bias[d].
            // The 4 acc regs are 4 consecutive rows (s) at fixed col (d) -> f16x4 store.
            f16* VT = (f16*)CvAlt;
#pragma unroll
            for (int MH = 0; MH < 2; ++MH)
#pragma unroll
                for (int NH = 0; NH < 2; ++NH)
#pragma unroll
                    for (int mi = 0; mi < 4; ++mi)
#pragma unroll
                        for (int nj = 0; nj < 2; ++nj) {
                            long gr = rowA0 + MH * 128 + wm2 * 64 + mi * 16 + l4 * 4;
                            int  gc = (int)rowB0 + NH * 128 + wn2 * 32 + nj * 16 + l15;
                            float bv_ = b2[gc];
                            long b = gr >> 11, sL = gr & 2047;
                            f16x4 o = { (f16)(acc[MH][NH][mi][nj][0] + bv_),
                                        (f16)(acc[MH][NH][mi][nj][1] + bv_),
                                        (f16)(acc[MH][NH][mi][nj][2] + bv_),
                                        (f16)(acc[MH][NH][mi][nj][3] + bv_) };
                            *(f16x4*)(VT + (b << 20) + ((long)gc << 11) + sL) = o;
                        }
            return;
        }
    }

    const float* bias = nullptr;
    if constexpr (QKV) bias = (bz == 0) ? b0 : b1;

#pragma unroll
    for (int MH = 0; MH < 2; ++MH)
#pragma unroll
        for (int NH = 0; NH < 2; ++NH)
#pragma unroll
            for (int mi = 0; mi < 4; ++mi)
#pragma unroll
                for (int nj = 0; nj < 2; ++nj) {
                    long gr = rowA0 + MH * 128 + wm2 * 64 + mi * 16 + l4 * 4;
                    int  gc = (int)rowB0 + NH * 128 + wn2 * 32 + nj * 16 + l15;
                    float bv_ = QKV ? bias[gc] : 0.f;
                    if constexpr (OUT_F16) {
                        f16* C = (f16*)Cv + bz * sC;
#pragma unroll
                        for (int r = 0; r < 4; ++r)
                            C[(gr + r) * (long)N + gc] = (f16)(acc[MH][NH][mi][nj][r] + bv_);
                    } else {
                        float* C = (float*)Cv + bz * sC;
#pragma unroll
                        for (int r = 0; r < 4; ++r)
                            C[(gr + r) * (long)N + gc] = acc[MH][NH][mi][nj][r] + bv_;
                    }
                }
}

// ============ PV: 128x128 tile, BK=64, depth-2 counted-vmcnt, swizzled LDS ============
#define PVSTAGE(BUF, K0)                                                                    \
  { _Pragma("unroll") for (int i_ = 0; i_ < 4; ++i_) {                                      \
      const f16* sa_ = A + (rowA0 + i_ * 32 + (tid >> 3)) * (long)K + (K0) + colSw;         \
      __builtin_amdgcn_global_load_lds(GADDR(sa_),                                          \
          LADDR(smem + (BUF) * 32768 + i_ * 4096 + wave * 1024), 16, 0, 0);                 \
      const f16* sb_ = Bt + (rowB0 + i_ * 32 + (tid >> 3)) * (long)K + (K0) + colSw;        \
      __builtin_amdgcn_global_load_lds(GADDR(sb_),                                          \
          LADDR(smem + (BUF) * 32768 + 16384 + i_ * 4096 + wave * 1024), 16, 0, 0);         \
    } }

__global__ __launch_bounds__(256) void k_pv(const f16* __restrict__ Ain,
                                            const f16* __restrict__ Btin,
                                            float* __restrict__ Cout,
                                            int N, int K,
                                            long sA, long sB, long sC) {
    int bxi, byi, bz;
    xcd_remap(bxi, byi, bz);
    const f16* A  = Ain  + bz * sA;
    const f16* Bt = Btin + bz * sB;
    __shared__ __align__(16) char smem[65536];
    const unsigned sbase = lds_u32(smem);

    const int tid = threadIdx.x;
    const int wave = tid >> 6, lane = tid & 63;
    const int l15 = lane & 15, l4 = lane >> 4;
    const int wm = (wave >> 1) * 64, wn = (wave & 1) * 64;
    const long rowA0 = (long)byi * 128;
    const long rowB0 = (long)bxi * 128;

    const unsigned sw = (unsigned)((l15 & 7) << 4);
    const unsigned cb0 = (unsigned)(l4 * 16) ^ sw;
    const unsigned cb1 = (unsigned)(64 + l4 * 16) ^ sw;
    const int colSw = (((tid & 7) ^ ((tid >> 3) & 7)) << 3);

    f32x4 acc[4][4] = {};

    const int nt = K >> 6;
    PVSTAGE(0, 0);
    int cur = 0;
    for (int t = 0; t < nt; ++t) {
        if (t + 1 < nt) { PVSTAGE(cur ^ 1, (t + 1) << 6); WAITV8; }
        else            { WAITV0; }
        __builtin_amdgcn_s_barrier();           // publish tile t

        f16x8 af[4][2], bf[4][2];
        const unsigned aB = sbase + (unsigned)cur * 32768u;
        const unsigned bB = aB + 16384u;
#pragma unroll
        for (int mi = 0; mi < 4; ++mi) {
            unsigned ra = wm + mi * 16 + l15;
            DSRD(af[mi][0], aB + ra * 128 + cb0);
            DSRD(af[mi][1], aB + ra * 128 + cb1);
        }
#pragma unroll
        for (int nj = 0; nj < 4; ++nj) {
            unsigned rb = wn + nj * 16 + l15;
            DSRD(bf[nj][0], bB + rb * 128 + cb0);
            DSRD(bf[nj][1], bB + rb * 128 + cb1);
        }
        WAITLG0;
        __builtin_amdgcn_sched_barrier(0);
        __builtin_amdgcn_s_setprio(1);
#pragma unroll
        for (int mi = 0; mi < 4; ++mi)
#pragma unroll
            for (int nj = 0; nj < 4; ++nj)
#pragma unroll
                for (int ks = 0; ks < 2; ++ks)
                    acc[mi][nj] = __builtin_amdgcn_mfma_f32_16x16x32_f16(
                        af[mi][ks], bf[nj][ks], acc[mi][nj], 0, 0, 0);
        __builtin_amdgcn_s_setprio(0);
        __builtin_amdgcn_s_barrier();           // all waves done reading buf[cur]
        cur ^= 1;
    }

    float* C = Cout + bz * sC;
#pragma unroll
    for (int mi = 0; mi < 4; ++mi)
#pragma unroll
        for (int nj = 0; nj < 4; ++nj) {
            long gr = rowA0 + wm + mi * 16 + l4 * 4;
            int  gc = (int)rowB0 + wn + nj * 16 + l15;
#pragma unroll
            for (int r = 0; r < 4; ++r)
                C[(gr + r) * (long)N + gc] = acc[mi][nj][r];
        }
}

// ---------------- row softmax in place: fp16 [2048 cols] ----------------
__global__ __launch_bounds__(256) void k_softmax(f16* __restrict__ P) {
    const long row = blockIdx.x;
    f16* p = P + row * 2048;
    const int tid = threadIdx.x, lane = tid & 63, wave = tid >> 6;

    f16x8 v = ((const f16x8*)p)[tid];
    float f[8];
#pragma unroll
    for (int j = 0; j < 8; ++j) f[j] = (float)v[j];
    float m = fmaxf(fmaxf(fmaxf(f[0], f[1]), fmaxf(f[2], f[3])),
                    fmaxf(fmaxf(f[4], f[5]), fmaxf(f[6], f[7])));
#pragma unroll
    for (int off = 32; off; off >>= 1) m = fmaxf(m, __shfl_xor(m, off));

    __shared__ float red[4];
    __shared__ float bc[2];
    if (lane == 0) red[wave] = m;
    __syncthreads();
    if (tid == 0) bc[0] = fmaxf(fmaxf(red[0], red[1]), fmaxf(red[2], red[3]));
    __syncthreads();
    m = bc[0];

    float e[8], sum = 0.f;
#pragma unroll
    for (int j = 0; j < 8; ++j) { e[j] = __expf(f[j] - m); sum += e[j]; }
#pragma unroll
    for (int off = 32; off; off >>= 1) sum += __shfl_xor(sum, off);
    if (lane == 0) red[wave] = sum;
    __syncthreads();
    if (tid == 0) bc[1] = (red[0] + red[1]) + (red[2] + red[3]);
    __syncthreads();
    float inv = 1.f / bc[1];

    f16x8 o;
#pragma unroll
    for (int j = 0; j < 8; ++j) o[j] = (f16)(e[j] * inv);
    ((f16x8*)p)[tid] = o;
}

extern "C" void kernel_launch(void* const* d_in, const int* in_sizes, int n_in,
                              void* d_out, int out_size, void* d_ws, size_t ws_size,
                              hipStream_t stream) {
    const float* x  = (const float*)d_in[0];
    const float* Wq = (const float*)d_in[1];
    const float* bq = (const float*)d_in[2];
    const float* Wk = (const float*)d_in[3];
    const float* bk = (const float*)d_in[4];
    const float* Wv = (const float*)d_in[5];
    const float* bv = (const float*)d_in[6];
    float* out = (float*)d_out;

    // ---- workspace layout (96 MiB, phase-aliased; see header comment) ----
    char* ws = (char*)d_ws;
    f16* vt = (f16*)(ws + 0);                  // [8][512][2048] fp16, written by proj
    f16* xh = (f16*)(ws + 33554432);           // [16384][512] fp16 (dead after proj)
    f16* Wt = (f16*)(ws + 50331648);           // [3][512][512] fp16 (dead after proj)
    f16* P8 = (f16*)(ws + 33554432);           // [8][2048][2048] scores->probs (overwrites xh/Wt)
    f16* qh = (f16*)d_out;                     // [16384][512] fp16 (d_out scratch, dead after scores)
    f16* kh = (f16*)((char*)d_out + 16777216); // [16384][512] fp16

    k_cvt_x<<<8192, 256, 0, stream>>>(x, xh);
    k_cvt_w<<<3072, 256, 0, stream>>>(Wq, Wk, Wv, Wt);

    // QKV projections: z=3, M=16384, N=512, K=512 (384 blocks).
    // bz 0,1 -> qh,kh row-major; bz 2 -> vt transposed.
    k_gemm8<true, true><<<dim3(2, 64, 3), 512, 0, stream>>>(
        xh, Wt, qh, vt, bq, bk, bv, 16384, 512, 512,
        0, (long)512 * 512, (long)16384 * 512);

    // scores: S[b] = q[b] k[b]^T, z=8, fp16 out (512 blocks)
    k_gemm8<true, false><<<dim3(8, 8, 8), 512, 0, stream>>>(
        qh, kh, P8, nullptr, nullptr, nullptr, nullptr, 2048, 2048, 512,
        (long)2048 * 512, (long)2048 * 512, (long)2048 * 2048);

    // softmax in place on all 16384 rows
    k_softmax<<<16384, 256, 0, stream>>>(P8);

    // out[b] = P[b] v[b], z=8, fp32 out (512 blocks)
    k_pv<<<dim3(4, 16, 8), 256, 0, stream>>>(
        P8, vt, out, 512, 2048,
        (long)2048 * 2048, (long)512 * 2048, (long)2048 * 512);
}

// Round 9
// 157.075 us; speedup vs baseline: 1.9047x; 1.0924x over previous
//
#include <hip/hip_runtime.h>
#include <hip/hip_fp16.h>

// WordAttention on MI355X: fp16 MFMA pipeline.
//   q,k,v = x@W + b (fp16);  S = q k^T (fp16, z=8);  P = softmax(S) in-place;  out = P v (fp32, z=8)
// ALL GEMMs: one 128x128 BK=64 depth-2 counted-vmcnt kernel (the R5-proven k_pv schedule),
//   swizzled LDS + asm ds_read_b128, XCD-swizzled grids.
//   proj bz==2 writes v TRANSPOSED (vt[b][d][s]) via f16x4 stores -> no transpose kernel.
//
// Memory plan (96 MiB ws + d_out as scratch):
//   ws:   vt[0,32M)  xh[32M,48M)+Wt[48M,50M)  P8[32M,96M) (P8 overwrites dead xh/Wt)
//   d_out: qh[0,16M) kh[16M,32M) during proj/scores; PV output overwrites (qh/kh dead).

typedef _Float16 f16;
typedef __attribute__((ext_vector_type(8))) _Float16 f16x8;
typedef __attribute__((ext_vector_type(4))) _Float16 f16x4;
typedef __attribute__((ext_vector_type(4))) float f32x4;
typedef __attribute__((address_space(3))) char lds_t;

#define GADDR(p) ((const __attribute__((address_space(1))) void*)(p))
#define LADDR(p) ((__attribute__((address_space(3))) void*)(p))

__device__ __forceinline__ unsigned lds_u32(void* p) {
    return (unsigned)(unsigned long long)(lds_t*)p;
}

// asm ds_read_b128: opaque to alias analysis; caller provides lgkmcnt waits.
#define DSRD(dst, a) asm volatile("ds_read_b128 %0, %1" : "=v"(dst) : "v"(a))
#define WAITV0 asm volatile("s_waitcnt vmcnt(0)" ::: "memory")
#define WAITV8 asm volatile("s_waitcnt vmcnt(8)" ::: "memory")
#define WAITLG0 asm volatile("s_waitcnt lgkmcnt(0)" ::: "memory")

// T1: XCD-aware bijective remap (requires nwg % 8 == 0; all our grids satisfy).
__device__ __forceinline__ void xcd_remap(int& bx, int& by, int& bz) {
    const int gx = gridDim.x, gy = gridDim.y;
    const int nwg = gx * gy * gridDim.z;
    const int f = (blockIdx.z * gy + blockIdx.y) * gx + blockIdx.x;
    int L = (f & 7) * (nwg >> 3) + (f >> 3);
    bx = L % gx; int r = L / gx; by = r % gy; bz = r / gy;
}

// ---------------- convert x: fp32 -> fp16 ----------------
__global__ __launch_bounds__(256) void k_cvt_x(const float* __restrict__ in,
                                               f16* __restrict__ out) {
    long i = (long)blockIdx.x * 256 + threadIdx.x;
    float4 v = ((const float4*)in)[i];
    f16x4 h = { (f16)v.x, (f16)v.y, (f16)v.z, (f16)v.w };
    ((f16x4*)out)[i] = h;
}

// ------------- convert+transpose weights: Wt[w][n][k] = W[w][k][n] -------------
__global__ __launch_bounds__(256) void k_cvt_w(const float* __restrict__ Wq,
                                               const float* __restrict__ Wk,
                                               const float* __restrict__ Wv,
                                               f16* __restrict__ Wt) {
    int id = blockIdx.x * 256 + threadIdx.x;
    int w = id >> 18, rem = id & 262143;
    int kk = rem >> 9, n = rem & 511;
    const float* W = (w == 0) ? Wq : (w == 1) ? Wk : Wv;
    Wt[((long)w << 18) + ((long)n << 9) + kk] = (f16)W[((long)kk << 9) + n];
}

// ============ 128x128 GEMM: C = A[M][K] * Bt[N][K]^T  (k_pv schedule, R5-proven) ============
// 256 threads = 4 waves (2x2), each 64x64. BK=64. LDS 64KB = 2 bufs x (A 16KB | B 16KB).
// Depth-2 pipeline: stage(t+1) -> vmcnt(8) -> barrier -> asm ds_read -> lgkmcnt(0) ->
// sched_barrier -> setprio(1) MFMA setprio(0) -> barrier.  Swizzle byte^=(r&7)<<4 both sides.
// QKV mode: z selects weight mat; bz<2 -> row-major C (+bias), bz==2 -> transposed vt write.

#define G128STAGE(BUF, K0)                                                                  \
  { _Pragma("unroll") for (int i_ = 0; i_ < 4; ++i_) {                                      \
      const f16* sa_ = A + (rowA0 + i_ * 32 + (tid >> 3)) * (long)K + (K0) + colSw;         \
      __builtin_amdgcn_global_load_lds(GADDR(sa_),                                          \
          LADDR(smem + (BUF) * 32768 + i_ * 4096 + wave * 1024), 16, 0, 0);                 \
      const f16* sb_ = Bt + (rowB0 + i_ * 32 + (tid >> 3)) * (long)K + (K0) + colSw;        \
      __builtin_amdgcn_global_load_lds(GADDR(sb_),                                          \
          LADDR(smem + (BUF) * 32768 + 16384 + i_ * 4096 + wave * 1024), 16, 0, 0);         \
    } }

template <bool OUT_F16, bool QKV>
__global__ __launch_bounds__(256) void k_g128(const f16* __restrict__ Ain,
                                              const f16* __restrict__ Btin,
                                              void* __restrict__ Cv,
                                              void* __restrict__ CvAlt,
                                              const float* __restrict__ b0,
                                              const float* __restrict__ b1,
                                              const float* __restrict__ b2,
                                              int N, int K,
                                              long sA, long sB, long sC) {
    int bxi, byi, bz;
    xcd_remap(bxi, byi, bz);
    const f16* A  = Ain  + bz * sA;
    const f16* Bt = Btin + bz * sB;
    __shared__ __align__(16) char smem[65536];
    const unsigned sbase = lds_u32(smem);

    const int tid = threadIdx.x;
    const int wave = tid >> 6, lane = tid & 63;
    const int l15 = lane & 15, l4 = lane >> 4;
    const int wm = (wave >> 1) * 64, wn = (wave & 1) * 64;
    const long rowA0 = (long)byi * 128;
    const long rowB0 = (long)bxi * 128;

    const unsigned sw = (unsigned)((l15 & 7) << 4);
    const unsigned cb0 = (unsigned)(l4 * 16) ^ sw;
    const unsigned cb1 = (unsigned)(64 + l4 * 16) ^ sw;
    const int colSw = (((tid & 7) ^ ((tid >> 3) & 7)) << 3);

    f32x4 acc[4][4] = {};

    const int nt = K >> 6;
    G128STAGE(0, 0);
    int cur = 0;
    for (int t = 0; t < nt; ++t) {
        if (t + 1 < nt) { G128STAGE(cur ^ 1, (t + 1) << 6); WAITV8; }
        else            { WAITV0; }
        __builtin_amdgcn_s_barrier();           // publish tile t (all waves' loads done)

        f16x8 af[4][2], bf[4][2];
        const unsigned aB = sbase + (unsigned)cur * 32768u;
        const unsigned bB = aB + 16384u;
#pragma unroll
        for (int mi = 0; mi < 4; ++mi) {
            unsigned ra = wm + mi * 16 + l15;
            DSRD(af[mi][0], aB + ra * 128 + cb0);
            DSRD(af[mi][1], aB + ra * 128 + cb1);
        }
#pragma unroll
        for (int nj = 0; nj < 4; ++nj) {
            unsigned rb = wn + nj * 16 + l15;
            DSRD(bf[nj][0], bB + rb * 128 + cb0);
            DSRD(bf[nj][1], bB + rb * 128 + cb1);
        }
        WAITLG0;
        __builtin_amdgcn_sched_barrier(0);
        __builtin_amdgcn_s_setprio(1);
#pragma unroll
        for (int mi = 0; mi < 4; ++mi)
#pragma unroll
            for (int nj = 0; nj < 4; ++nj)
#pragma unroll
                for (int ks = 0; ks < 2; ++ks)
                    acc[mi][nj] = __builtin_amdgcn_mfma_f32_16x16x32_f16(
                        af[mi][ks], bf[nj][ks], acc[mi][nj], 0, 0, 0);
        __builtin_amdgcn_s_setprio(0);
        __builtin_amdgcn_s_barrier();           // all waves done reading buf[cur]
        cur ^= 1;
    }

    // ---- epilogue: C/D layout col = lane&15, row = (lane>>4)*4 + reg [m89-verified] ----
    if constexpr (QKV) {
        if (bz == 2) {
            // v path: write TRANSPOSED vt[b][d][sLocal] = acc + bias[d].
            // The 4 acc regs are 4 consecutive rows (s) at fixed col (d) -> f16x4 store.
            f16* VT = (f16*)CvAlt;
#pragma unroll
            for (int mi = 0; mi < 4; ++mi)
#pragma unroll
                for (int nj = 0; nj < 4; ++nj) {
                    long gr = rowA0 + wm + mi * 16 + l4 * 4;
                    int  gc = (int)rowB0 + wn + nj * 16 + l15;
                    float bv_ = b2[gc];
                    long b = gr >> 11, sL = gr & 2047;
                    f16x4 o = { (f16)(acc[mi][nj][0] + bv_),
                                (f16)(acc[mi][nj][1] + bv_),
                                (f16)(acc[mi][nj][2] + bv_),
                                (f16)(acc[mi][nj][3] + bv_) };
                    *(f16x4*)(VT + (b << 20) + ((long)gc << 11) + sL) = o;
                }
            return;
        }
    }

    const float* bias = nullptr;
    if constexpr (QKV) bias = (bz == 0) ? b0 : b1;

#pragma unroll
    for (int mi = 0; mi < 4; ++mi)
#pragma unroll
        for (int nj = 0; nj < 4; ++nj) {
            long gr = rowA0 + wm + mi * 16 + l4 * 4;
            int  gc = (int)rowB0 + wn + nj * 16 + l15;
            float bv_ = QKV ? bias[gc] : 0.f;
            if constexpr (OUT_F16) {
                f16* C = (f16*)Cv + bz * sC;
#pragma unroll
                for (int r = 0; r < 4; ++r)
                    C[(gr + r) * (long)N + gc] = (f16)(acc[mi][nj][r] + bv_);
            } else {
                float* C = (float*)Cv + bz * sC;
#pragma unroll
                for (int r = 0; r < 4; ++r)
                    C[(gr + r) * (long)N + gc] = acc[mi][nj][r] + bv_;
            }
        }
}

// ---------------- row softmax in place: fp16 [2048 cols] ----------------
__global__ __launch_bounds__(256) void k_softmax(f16* __restrict__ P) {
    const long row = blockIdx.x;
    f16* p = P + row * 2048;
    const int tid = threadIdx.x, lane = tid & 63, wave = tid >> 6;

    f16x8 v = ((const f16x8*)p)[tid];
    float f[8];
#pragma unroll
    for (int j = 0; j < 8; ++j) f[j] = (float)v[j];
    float m = fmaxf(fmaxf(fmaxf(f[0], f[1]), fmaxf(f[2], f[3])),
                    fmaxf(fmaxf(f[4], f[5]), fmaxf(f[6], f[7])));
#pragma unroll
    for (int off = 32; off; off >>= 1) m = fmaxf(m, __shfl_xor(m, off));

    __shared__ float red[4];
    __shared__ float bc[2];
    if (lane == 0) red[wave] = m;
    __syncthreads();
    if (tid == 0) bc[0] = fmaxf(fmaxf(red[0], red[1]), fmaxf(red[2], red[3]));
    __syncthreads();
    m = bc[0];

    float e[8], sum = 0.f;
#pragma unroll
    for (int j = 0; j < 8; ++j) { e[j] = __expf(f[j] - m); sum += e[j]; }
#pragma unroll
    for (int off = 32; off; off >>= 1) sum += __shfl_xor(sum, off);
    if (lane == 0) red[wave] = sum;
    __syncthreads();
    if (tid == 0) bc[1] = (red[0] + red[1]) + (red[2] + red[3]);
    __syncthreads();
    float inv = 1.f / bc[1];

    f16x8 o;
#pragma unroll
    for (int j = 0; j < 8; ++j) o[j] = (f16)(e[j] * inv);
    ((f16x8*)p)[tid] = o;
}

extern "C" void kernel_launch(void* const* d_in, const int* in_sizes, int n_in,
                              void* d_out, int out_size, void* d_ws, size_t ws_size,
                              hipStream_t stream) {
    const float* x  = (const float*)d_in[0];
    const float* Wq = (const float*)d_in[1];
    const float* bq = (const float*)d_in[2];
    const float* Wk = (const float*)d_in[3];
    const float* bk = (const float*)d_in[4];
    const float* Wv = (const float*)d_in[5];
    const float* bv = (const float*)d_in[6];
    float* out = (float*)d_out;

    // ---- workspace layout (96 MiB, phase-aliased; see header comment) ----
    char* ws = (char*)d_ws;
    f16* vt = (f16*)(ws + 0);                  // [8][512][2048] fp16, written by proj
    f16* xh = (f16*)(ws + 33554432);           // [16384][512] fp16 (dead after proj)
    f16* Wt = (f16*)(ws + 50331648);           // [3][512][512] fp16 (dead after proj)
    f16* P8 = (f16*)(ws + 33554432);           // [8][2048][2048] scores->probs (overwrites xh/Wt)
    f16* qh = (f16*)d_out;                     // [16384][512] fp16 (d_out scratch, dead after scores)
    f16* kh = (f16*)((char*)d_out + 16777216); // [16384][512] fp16

    k_cvt_x<<<8192, 256, 0, stream>>>(x, xh);
    k_cvt_w<<<3072, 256, 0, stream>>>(Wq, Wk, Wv, Wt);

    // QKV projections: z=3, M=16384, N=512, K=512 (1536 blocks, 2/CU resident).
    // bz 0,1 -> qh,kh row-major; bz 2 -> vt transposed.
    k_g128<true, true><<<dim3(4, 128, 3), 256, 0, stream>>>(
        xh, Wt, qh, vt, bq, bk, bv, 512, 512,
        0, (long)512 * 512, (long)16384 * 512);

    // scores: S[b] = q[b] k[b]^T, z=8, fp16 out (2048 blocks)
    k_g128<true, false><<<dim3(16, 16, 8), 256, 0, stream>>>(
        qh, kh, P8, nullptr, nullptr, nullptr, nullptr, 2048, 512,
        (long)2048 * 512, (long)2048 * 512, (long)2048 * 2048);

    // softmax in place on all 16384 rows
    k_softmax<<<16384, 256, 0, stream>>>(P8);

    // out[b] = P[b] v[b], z=8, fp32 out (512 blocks)
    k_g128<false, false><<<dim3(4, 16, 8), 256, 0, stream>>>(
        P8, vt, out, nullptr, nullptr, nullptr, nullptr, 512, 2048,
        (long)2048 * 2048, (long)512 * 2048, (long)2048 * 512);
}